// Round 11
// baseline (370.297 us; speedup 1.0000x reference)
//
#include <hip/hip_runtime.h>
#include <math.h>
#include <utility>

// N = 100000 nodes, SEQ = 16, layers: 3 ->16 ->32 ->64 ->128 ->256 ->12(log_softmax)
// bf16 MFMA, barrier-free K-loop, MT=2 traffic-optimized tiling:
//   Wave tile = 64 rows x WN cols (MT=2 row-subtiles) -> each B fragment feeds 2 MFMAs,
//   halving B traffic per MFMA (R10 showed the kernel is vmem-throughput-bound:
//   1.5 KB/MFMA; this build is 1.0).
//   A (gathered): global_load_lds into per-wave DOUBLE-buffered LDS (8 KB/buf),
//   chunk-XOR swizzle at the source address -> conflict-free-ish ds_read_b128.
//   idx: depth-2 prefetch ring (%3) in regs; B: VGPR double-buffer from frag-major
//   pre-swizzled weights (L2-resident). Manual exact s_waitcnt vmcnt(N); sched_barrier
//   fences pin memory-op order only. NO __syncthreads in the K-loop.

typedef __bf16 bf16x8 __attribute__((ext_vector_type(8)));
typedef float f32x16 __attribute__((ext_vector_type(16)));

template <int V> using ic = std::integral_constant<int, V>;

template <typename F, int... Is>
__device__ __forceinline__ void static_for_impl(F&& f, std::integer_sequence<int, Is...>) {
    (f(ic<Is>{}), ...);
}
template <int N_, typename F>
__device__ __forceinline__ void static_for(F&& f) {
    static_for_impl(static_cast<F&&>(f), std::make_integer_sequence<int, N_>{});
}

template <int N_>
__device__ __forceinline__ void wait_vmcnt() {
    static_assert(N_ <= 63, "vmcnt range");
    // gfx9 encoding: vmcnt[3:0] | expcnt<<4 | lgkmcnt<<8 | vmcnt[5:4]<<14 (exp/lgkm = no-wait)
    __builtin_amdgcn_s_waitcnt((N_ & 0xF) | (0x7 << 4) | (0xF << 8) | ((N_ >> 4) << 14));
}

// fence: pin VMEM/DS order, allow ALU/SALU/MFMA to cross
__device__ __forceinline__ void memfence_sched() { __builtin_amdgcn_sched_barrier(0x000F); }

__device__ __forceinline__ float elu_f(float v) { return v > 0.f ? v : expm1f(v); }

// ------------------------------------------------ weight prep: fp32 -> bf16, frag-major swizzle
// dst chunk ((k/64)*8 + (k%64)/8)*COUT + col, element k%8  <-  src[col*K + k]
template <int K, int C>
__device__ __forceinline__ void swz_one(const float* __restrict__ src, __bf16* __restrict__ dst, int j)
{
    int col = j / K;          // K is pow2
    int k = j & (K - 1);
    int chunk = ((k >> 6) * 8 + ((k & 63) >> 3)) * C + col;
    dst[chunk * 8 + (k & 7)] = (__bf16)src[j];
}

__global__ __launch_bounds__(256) void cvt_swz_kernel(const float* __restrict__ w1,
                                                      const float* __restrict__ w2,
                                                      const float* __restrict__ w3,
                                                      const float* __restrict__ f1,
                                                      const float* __restrict__ f2,
                                                      __bf16* __restrict__ d1,
                                                      __bf16* __restrict__ d2,
                                                      __bf16* __restrict__ d3,
                                                      __bf16* __restrict__ df1,
                                                      __bf16* __restrict__ df2)
{
    int i = blockIdx.x * 256 + threadIdx.x;
    if (i < 8192)        swz_one<256, 32>(w1, d1, i);
    else if (i < 40960)  swz_one<512, 64>(w2, d2, i - 8192);
    else if (i < 172032) swz_one<1024, 128>(w3, d3, i - 40960);
    else if (i < 204800) swz_one<128, 256>(f1, df1, i - 172032);
    else if (i < 207872) df2[i - 204800] = (__bf16)f2[i - 204800];   // fc2 stays row-major
}

// ------------------------------------------------ idx transpose: idxT[s*N + n] = idx[n*16 + s]
__global__ __launch_bounds__(256) void idxT_kernel(const int* __restrict__ idx,
                                                   int* __restrict__ idxT, int N)
{
    int i = blockIdx.x * 256 + threadIdx.x;
    if (i >= N * 16) return;
    int n = i >> 4, s = i & 15;
    idxT[s * N + n] = idx[i];
}

// ---------------------------------------------------------------- fc0: [N,3] -> [N,16] bf16
__global__ __launch_bounds__(256) void fc0_kernel(const float* __restrict__ x,
                                                  const float* __restrict__ w,
                                                  const float* __restrict__ b,
                                                  __bf16* __restrict__ h0, int N)
{
    int n = blockIdx.x * 256 + threadIdx.x;
    if (n >= N) return;
    float x0 = x[n * 3 + 0], x1 = x[n * 3 + 1], x2 = x[n * 3 + 2];
    __bf16 ob[16];
#pragma unroll
    for (int j = 0; j < 16; ++j)
        ob[j] = (__bf16)elu_f(w[j * 3 + 0] * x0 + w[j * 3 + 1] * x1 + w[j * 3 + 2] * x2 + b[j]);
    int4* dst = (int4*)&h0[(size_t)n * 16];
    dst[0] = *(int4*)&ob[0];
    dst[1] = *(int4*)&ob[8];
}

// ------------------------------------------- MT=2 pipelined MFMA gather-GEMM
template <int CIN, int S, int COUT_B, int COUT_TOT, int TILE_M, int RW, int CW,
          bool GATHER, int MINW, int NN>
__global__ __launch_bounds__(256, MINW) void mfma_layer(const __bf16* __restrict__ hin,
                                                        const int* __restrict__ idxT,
                                                        const __bf16* __restrict__ Wsw,
                                                        const float* __restrict__ bias,
                                                        __bf16* __restrict__ hout)
{
    constexpr int K = CIN * S;
    constexpr int NSTEP = K / 64;
    static_assert(K % 64 == 0, "K%64");
    constexpr int WM = TILE_M / RW;        // rows per wave (=64)
    constexpr int WN = COUT_B / CW;
    constexpr int MT = WM / 32;            // row subtiles per wave (=2)
    constexpr int NT = WN / 32;
    constexpr int IPS = GATHER ? (64 / CIN) : 1;
    constexpr int D = WM / 8;              // DMA insts per step per wave (=8)
    constexpr int Bn = NT * 4;             // B vmem loads per step
    constexpr int I = GATHER ? D : 0;      // idx vmem loads per step
    constexpr int NBUFS = 2;
    static_assert(RW * CW == 4, "4 waves");
    static_assert(WM == 64, "two 32-row subtiles per wave");

    constexpr int AB = 4 * NBUFS * WM * 128;              // A staging bytes (= 65536)
    constexpr int CB = TILE_M * (COUT_B + 8) * 2;         // epilogue staging bytes
    constexpr int SH = AB > CB ? AB : CB;
    __shared__ __align__(16) char smem[SH];

    const int tid = threadIdx.x;
    const int lane = tid & 63;
    const int w = tid >> 6;
    const int wr = w / CW;
    const int wc = w % CW;
    const int ml = lane & 31;
    const int kh = lane >> 5;
    const int m0 = blockIdx.x * TILE_M;
    const int col0 = blockIdx.y * COUT_B;
    const int rbase = m0 + wr * WM;

    char* const Aw = smem + w * (NBUFS * WM * 128);   // this wave's A double buffer (16 KB)

    // ---- per-lane DMA geometry (computed once)
    int ioff[GATHER ? D : 1];      // gather: j*NN + clamped row
    int koff[GATHER ? D : 1];      // gather: channel offset within node row
    int gmr[GATHER ? 1 : D];       // dense: clamped rows
    int coff[GATHER ? 1 : D];      // dense: chunk element offset
#pragma unroll
    for (int i = 0; i < D; ++i) {
        int r = i * 8 + (lane >> 3);
        int c = (lane & 7) ^ (r & 7);
        int gm = rbase + r; if (gm >= NN) gm = NN - 1;
        if constexpr (GATHER) {
            ioff[i] = ((c * 8) / CIN) * NN + gm;
            koff[i] = (c * 8) & (CIN - 1);
        } else {
            gmr[i] = gm;
            coff[i] = c * 8;
        }
    }

    bf16x8 bfr[2][NT][4];
    int myIdx[GATHER ? 3 : 1][GATHER ? D : 1];

    const __bf16* wlane = Wsw + ((size_t)(col0 + wc * WN + ml) + (size_t)kh * COUT_TOT) * 8;

    auto loadB = [&](auto sc) {
        constexpr int s = decltype(sc)::value;
        if constexpr (s < NSTEP) {
#pragma unroll
            for (int ni = 0; ni < NT; ++ni)
#pragma unroll
                for (int ks = 0; ks < 4; ++ks)
                    bfr[s & 1][ni][ks] = *(const bf16x8*)(wlane
                        + (size_t)(s * 8 + ks * 2) * COUT_TOT * 8 + ni * 32 * 8);
        }
    };
    auto loadIdxS = [&](auto sc) {
        constexpr int s = decltype(sc)::value;
        if constexpr (GATHER && s < NSTEP) {
#pragma unroll
            for (int i = 0; i < D; ++i)
                myIdx[s % 3][i] = idxT[(s * IPS) * NN + ioff[i]];
        }
    };
    auto issueDMA = [&](auto sc) {
        constexpr int s = decltype(sc)::value;
        if constexpr (s < NSTEP) {
            char* base = Aw + (s % NBUFS) * (WM * 128);
#pragma unroll
            for (int i = 0; i < D; ++i) {
                const __bf16* src;
                if constexpr (GATHER)
                    src = hin + (size_t)myIdx[s % 3][i] * CIN + koff[i];
                else
                    src = hin + (size_t)gmr[i] * K + s * 64 + coff[i];
                __builtin_amdgcn_global_load_lds(
                    (const __attribute__((address_space(1))) void*)src,
                    (__attribute__((address_space(3))) void*)(base + i * 1024),
                    16, 0, 0);
            }
        }
    };

    f32x16 acc[MT][NT];
#pragma unroll
    for (int mi = 0; mi < MT; ++mi)
#pragma unroll
        for (int ni = 0; ni < NT; ++ni) { f32x16 z = {}; acc[mi][ni] = z; }

    // ---- prologue (mirrors in-loop group order so vmcnt counts stay exact)
    loadIdxS(ic<0>{});
    loadIdxS(ic<1>{});
    memfence_sched();
    loadB(ic<0>{});
    memfence_sched();
    issueDMA(ic<0>{});
    memfence_sched();
    loadIdxS(ic<2>{});
    memfence_sched();

    // ---- K-loop: [B(s+1)] [DMA(s+1)] [idx(s+3)] | wait DMA(s) | ds_read + MFMA
    static_for<NSTEP>([&](auto sc) {
        constexpr int s = decltype(sc)::value;
        loadB(ic<s + 1>{});
        memfence_sched();
        issueDMA(ic<s + 1>{});
        memfence_sched();
        loadIdxS(ic<s + 3>{});
        memfence_sched();
        // ops younger than DMA(s)'s last inst:
        //   [step s-1 / prologue]: idx(s+2); [step s]: B(s+1), DMA(s+1), idx(s+3)
        constexpr int NW = I * (s + 2 < NSTEP) + (Bn + D) * (s + 1 < NSTEP)
                         + I * (s + 3 < NSTEP);
        wait_vmcnt<NW>();                      // A(s) now resident in this wave's LDS buf
        memfence_sched();

        const char* base = Aw + (s % NBUFS) * (WM * 128);
        bf16x8 afr[MT][4];
#pragma unroll
        for (int mi = 0; mi < MT; ++mi)
#pragma unroll
            for (int ks = 0; ks < 4; ++ks) {
                int cb = ks * 2 + kh;
                afr[mi][ks] = *(const bf16x8*)(base + ((mi * 32 + ml) * 8 + (cb ^ (ml & 7))) * 16);
            }
#pragma unroll
        for (int ks = 0; ks < 4; ++ks)
#pragma unroll
            for (int mi = 0; mi < MT; ++mi)
#pragma unroll
                for (int ni = 0; ni < NT; ++ni)
                    acc[mi][ni] = __builtin_amdgcn_mfma_f32_32x32x16_bf16(
                        afr[mi][ks], bfr[s & 1][ni][ks], acc[mi][ni], 0, 0, 0);
    });

    // ---- epilogue: acc -> LDS (reuse A region) -> coalesced int4 stores
    __syncthreads();
    __bf16* Cs = (__bf16*)smem;
    constexpr int LDC = COUT_B + 8;
#pragma unroll
    for (int ni = 0; ni < NT; ++ni) {
        const int col = wc * WN + ni * 32 + ml;
        const float bv = bias[col0 + col];
#pragma unroll
        for (int mi = 0; mi < MT; ++mi) {
#pragma unroll
            for (int r = 0; r < 16; ++r) {
                int row = wr * WM + mi * 32 + ((r & 3) + 8 * (r >> 2) + 4 * kh);
                Cs[row * LDC + col] = (__bf16)elu_f(acc[mi][ni][r] + bv);
            }
        }
    }
    __syncthreads();
    constexpr int C8 = COUT_B / 8;
#pragma unroll
    for (int j2 = tid; j2 < TILE_M * C8; j2 += 256) {
        int row = j2 / C8, c8 = j2 % C8;
        int gm = m0 + row;
        if (gm < NN)
            *(int4*)&hout[(size_t)gm * COUT_TOT + col0 + c8 * 8] = *(int4*)&Cs[row * LDC + c8 * 8];
    }
}

// ---------------------------------------------------------------- fc2 + log_softmax: [N,256] bf16 -> [N,12] f32
__global__ __launch_bounds__(256) void fc2_kernel(const __bf16* __restrict__ h4,
                                                  const __bf16* __restrict__ Wb,  // [12,256] bf16
                                                  const float* __restrict__ bias,
                                                  float* __restrict__ out, int N)
{
    const int lane = threadIdx.x & 63;
    const int w = threadIdx.x >> 6;
    const int c = lane & 31;
    const int half = lane >> 5;

    bf16x8 wreg[12];
#pragma unroll
    for (int o = 0; o < 12; ++o)
        wreg[o] = *(const bf16x8*)&Wb[o * 256 + c * 8];

    const int base = blockIdx.x * 32 + w * 8;
#pragma unroll
    for (int p = 0; p < 4; ++p) {
        int n = base + p * 2 + half;
        bool valid = n < N;
        int nn = valid ? n : N - 1;
        bf16x8 h = *(const bf16x8*)&h4[(size_t)nn * 256 + c * 8];
        float hf[8];
#pragma unroll
        for (int j = 0; j < 8; ++j) hf[j] = (float)h[j];
        float pr[12];
#pragma unroll
        for (int o = 0; o < 12; ++o) {
            float s = 0.f;
#pragma unroll
            for (int j = 0; j < 8; ++j) s += hf[j] * (float)wreg[o][j];
            pr[o] = s;
        }
#pragma unroll
        for (int off = 16; off > 0; off >>= 1) {
#pragma unroll
            for (int o = 0; o < 12; ++o) pr[o] += __shfl_down(pr[o], off, 32);
        }
        if (c == 0 && valid) {
            float logits[12], mx = -1e30f;
#pragma unroll
            for (int o = 0; o < 12; ++o) {
                logits[o] = pr[o] + bias[o];
                mx = fmaxf(mx, logits[o]);
            }
            float s = 0.f;
#pragma unroll
            for (int o = 0; o < 12; ++o) s += expf(logits[o] - mx);
            float lse = mx + logf(s);
#pragma unroll
            for (int o = 0; o < 12; ++o) out[(size_t)n * 12 + o] = logits[o] - lse;
        }
    }
}

extern "C" void kernel_launch(void* const* d_in, const int* in_sizes, int n_in,
                              void* d_out, int out_size, void* d_ws, size_t ws_size,
                              hipStream_t stream)
{
    const int N = 100000;
    const float* x     = (const float*)d_in[0];
    const int*   idx   = (const int*)  d_in[1];
    const float* fc0_w = (const float*)d_in[2];
    const float* fc0_b = (const float*)d_in[3];
    const float* w1    = (const float*)d_in[4];
    const float* b1    = (const float*)d_in[5];
    const float* w2    = (const float*)d_in[6];
    const float* b2    = (const float*)d_in[7];
    const float* w3    = (const float*)d_in[8];
    const float* b3    = (const float*)d_in[9];
    const float* fc1_w = (const float*)d_in[10];
    const float* fc1_b = (const float*)d_in[11];
    const float* fc2_w = (const float*)d_in[12];
    const float* fc2_b = (const float*)d_in[13];
    float* out = (float*)d_out;

    // ---- workspace layout
    char* ws = (char*)d_ws;
    const int n_w1 = 32 * 256, n_w2 = 64 * 512, n_w3 = 128 * 1024, n_fc1 = 256 * 128, n_fc2 = 12 * 256;
    const int n_wb = n_w1 + n_w2 + n_w3 + n_fc1 + n_fc2;   // 207872
    __bf16* w1b = (__bf16*)ws;
    __bf16* w2b = w1b + n_w1;
    __bf16* w3b = w2b + n_w2;
    __bf16* f1b = w3b + n_w3;
    __bf16* f2b = f1b + n_fc1;
    size_t off = ((size_t)n_wb * 2 + 4095) & ~(size_t)4095;
    int* idxT = (int*)(ws + off);      off += (size_t)N * 16 * 4;
    __bf16* h0 = (__bf16*)(ws + off);  off += (size_t)N * 16 * 2;
    __bf16* h1 = (__bf16*)(ws + off);  off += (size_t)N * 32 * 2;
    __bf16* h2 = (__bf16*)(ws + off);  off += (size_t)N * 64 * 2;
    __bf16* h3 = (__bf16*)(ws + off);  off += (size_t)N * 128 * 2;
    __bf16* h4 = (__bf16*)(ws + off);  off += (size_t)N * 256 * 2;

    cvt_swz_kernel<<<(n_wb + 255) / 256, 256, 0, stream>>>(w1, w2, w3, fc1_w, fc2_w,
                                                           w1b, w2b, w3b, f1b, f2b);
    idxT_kernel<<<(N * 16 + 255) / 256, 256, 0, stream>>>(idx, idxT, N);
    fc0_kernel<<<(N + 255) / 256, 256, 0, stream>>>(x, fc0_w, fc0_b, h0, N);

    // spiral1: 16ch x16 -> 32. TILE 256 (RW=4, CW=1), wave 64x32, NSTEP=4.
    mfma_layer<16, 16, 32, 32, 256, 4, 1, true, 2, 100000>
        <<<dim3((N + 255) / 256, 1), 256, 0, stream>>>(h0, idxT, w1b, b1, h1);
    // spiral2: 32ch x16 -> 64. TILE 256 (RW=4, CW=1), wave 64x64, NSTEP=8.
    mfma_layer<32, 16, 64, 64, 256, 4, 1, true, 2, 100000>
        <<<dim3((N + 255) / 256, 1), 256, 0, stream>>>(h1, idxT, w2b, b2, h2);
    // spiral3: 64ch x16 -> 128. TILE 128 (RW=2, CW=2), wave 64x64, NSTEP=16.
    mfma_layer<64, 16, 128, 128, 128, 2, 2, true, 2, 100000>
        <<<dim3((N + 127) / 128, 1), 256, 0, stream>>>(h2, idxT, w3b, b3, h3);
    // fc1: dense 128 -> 256, 2 column-blocks of 128. TILE 128, wave 64x64, NSTEP=2.
    mfma_layer<128, 1, 128, 256, 128, 2, 2, false, 2, 100000>
        <<<dim3((N + 127) / 128, 2), 256, 0, stream>>>(h3, nullptr, f1b, fc1_b, h4);
    // fc2 + log_softmax
    fc2_kernel<<<(N + 31) / 32, 256, 0, stream>>>(h4, f2b, fc2_b, out, N);
}

// Round 12
// 271.729 us; speedup vs baseline: 1.3627x; 1.3627x over previous
//
#include <hip/hip_runtime.h>
#include <math.h>
#include <utility>

// N = 100000 nodes, SEQ = 16, layers: 3 ->16 ->32 ->64 ->128 ->256 ->12(log_softmax)
// bf16 MFMA, barrier-free K-loop, depth-1 gather pipeline (R8-proven):
//   A (gathered): global_load_lds into per-wave DOUBLE-buffered LDS; chunk-XOR swizzle
//   at the source address -> conflict-free ds_read_b128.
//   idx: depth-2 prefetch ring (%3). B: VGPR double-buffer from frag-major pre-swizzled
//   weights (L2-resident). Manual exact s_waitcnt vmcnt(N); sched_barrier fences pin
//   memory-op order only. NO __syncthreads in the K-loop. LDS reused for C epilogue.
// R11 lesson: MT=2 (64KB LDS) kills TLP -> regression. This build: MT=1/32KB everywhere;
// the one change vs R8 is spiral2 CW=2 -> CW=1 (removes 2x duplicated A-gather traffic).

typedef __bf16 bf16x8 __attribute__((ext_vector_type(8)));
typedef float f32x16 __attribute__((ext_vector_type(16)));

template <int V> using ic = std::integral_constant<int, V>;

template <typename F, int... Is>
__device__ __forceinline__ void static_for_impl(F&& f, std::integer_sequence<int, Is...>) {
    (f(ic<Is>{}), ...);
}
template <int N_, typename F>
__device__ __forceinline__ void static_for(F&& f) {
    static_for_impl(static_cast<F&&>(f), std::make_integer_sequence<int, N_>{});
}

template <int N_>
__device__ __forceinline__ void wait_vmcnt() {
    static_assert(N_ <= 63, "vmcnt range");
    // gfx9 encoding: vmcnt[3:0] | expcnt<<4 | lgkmcnt<<8 | vmcnt[5:4]<<14 (exp/lgkm = no-wait)
    __builtin_amdgcn_s_waitcnt((N_ & 0xF) | (0x7 << 4) | (0xF << 8) | ((N_ >> 4) << 14));
}

// fence: pin VMEM/DS order, allow ALU/SALU/MFMA to cross
__device__ __forceinline__ void memfence_sched() { __builtin_amdgcn_sched_barrier(0x000F); }

__device__ __forceinline__ float elu_f(float v) { return v > 0.f ? v : expm1f(v); }

// ------------------------------------------------ weight prep: fp32 -> bf16, frag-major swizzle
// dst chunk ((k/64)*8 + (k%64)/8)*COUT + col, element k%8  <-  src[col*K + k]
template <int K, int C>
__device__ __forceinline__ void swz_one(const float* __restrict__ src, __bf16* __restrict__ dst, int j)
{
    int col = j / K;          // K is pow2
    int k = j & (K - 1);
    int chunk = ((k >> 6) * 8 + ((k & 63) >> 3)) * C + col;
    dst[chunk * 8 + (k & 7)] = (__bf16)src[j];
}

__global__ __launch_bounds__(256) void cvt_swz_kernel(const float* __restrict__ w1,
                                                      const float* __restrict__ w2,
                                                      const float* __restrict__ w3,
                                                      const float* __restrict__ f1,
                                                      const float* __restrict__ f2,
                                                      __bf16* __restrict__ d1,
                                                      __bf16* __restrict__ d2,
                                                      __bf16* __restrict__ d3,
                                                      __bf16* __restrict__ df1,
                                                      __bf16* __restrict__ df2)
{
    int i = blockIdx.x * 256 + threadIdx.x;
    if (i < 8192)        swz_one<256, 32>(w1, d1, i);
    else if (i < 40960)  swz_one<512, 64>(w2, d2, i - 8192);
    else if (i < 172032) swz_one<1024, 128>(w3, d3, i - 40960);
    else if (i < 204800) swz_one<128, 256>(f1, df1, i - 172032);
    else if (i < 207872) df2[i - 204800] = (__bf16)f2[i - 204800];   // fc2 stays row-major
}

// ------------------------------------------------ idx transpose: idxT[s*N + n] = idx[n*16 + s]
__global__ __launch_bounds__(256) void idxT_kernel(const int* __restrict__ idx,
                                                   int* __restrict__ idxT, int N)
{
    int i = blockIdx.x * 256 + threadIdx.x;
    if (i >= N * 16) return;
    int n = i >> 4, s = i & 15;
    idxT[s * N + n] = idx[i];
}

// ---------------------------------------------------------------- fc0: [N,3] -> [N,16] bf16
__global__ __launch_bounds__(256) void fc0_kernel(const float* __restrict__ x,
                                                  const float* __restrict__ w,
                                                  const float* __restrict__ b,
                                                  __bf16* __restrict__ h0, int N)
{
    int n = blockIdx.x * 256 + threadIdx.x;
    if (n >= N) return;
    float x0 = x[n * 3 + 0], x1 = x[n * 3 + 1], x2 = x[n * 3 + 2];
    __bf16 ob[16];
#pragma unroll
    for (int j = 0; j < 16; ++j)
        ob[j] = (__bf16)elu_f(w[j * 3 + 0] * x0 + w[j * 3 + 1] * x1 + w[j * 3 + 2] * x2 + b[j]);
    int4* dst = (int4*)&h0[(size_t)n * 16];
    dst[0] = *(int4*)&ob[0];
    dst[1] = *(int4*)&ob[8];
}

// ------------------------------------------- depth-1 pipelined MFMA gather-GEMM (WM 32 or 64)
template <int CIN, int S, int COUT_B, int COUT_TOT, int TILE_M, int RW, int CW,
          bool GATHER, int MINW, int NN>
__global__ __launch_bounds__(256, MINW) void mfma_layer(const __bf16* __restrict__ hin,
                                                        const int* __restrict__ idxT,
                                                        const __bf16* __restrict__ Wsw,
                                                        const float* __restrict__ bias,
                                                        __bf16* __restrict__ hout)
{
    constexpr int K = CIN * S;
    constexpr int NSTEP = K / 64;
    static_assert(K % 64 == 0, "K%64");
    constexpr int WM = TILE_M / RW;        // rows per wave
    constexpr int WN = COUT_B / CW;
    constexpr int MT = WM / 32;            // row subtiles per wave
    constexpr int NT = WN / 32;
    constexpr int IPS = GATHER ? (64 / CIN) : 1;
    constexpr int D = WM / 8;              // DMA insts per step per wave
    constexpr int Bn = NT * 4;             // B vmem loads per step
    constexpr int I = GATHER ? D : 0;      // idx vmem loads per step
    constexpr int NBUFS = 2;
    static_assert(RW * CW == 4, "4 waves");
    static_assert(WM == 32 || WM == 64, "1-2 row subtiles per wave");

    constexpr int AB = 4 * NBUFS * WM * 128;              // A staging bytes
    constexpr int CB = TILE_M * (COUT_B + 8) * 2;         // epilogue staging bytes
    constexpr int SH = AB > CB ? AB : CB;
    __shared__ __align__(16) char smem[SH];

    const int tid = threadIdx.x;
    const int lane = tid & 63;
    const int w = tid >> 6;
    const int wr = w / CW;
    const int wc = w % CW;
    const int ml = lane & 31;
    const int kh = lane >> 5;
    const int m0 = blockIdx.x * TILE_M;
    const int col0 = blockIdx.y * COUT_B;
    const int rbase = m0 + wr * WM;

    char* const Aw = smem + w * (NBUFS * WM * 128);   // this wave's A double buffer

    // ---- per-lane DMA geometry (computed once)
    int ioff[GATHER ? D : 1];      // gather: j*NN + clamped row
    int koff[GATHER ? D : 1];      // gather: channel offset within node row
    int gmr[GATHER ? 1 : D];       // dense: clamped rows
    int coff[GATHER ? 1 : D];      // dense: chunk element offset
#pragma unroll
    for (int i = 0; i < D; ++i) {
        int r = i * 8 + (lane >> 3);
        int c = (lane & 7) ^ (r & 7);
        int gm = rbase + r; if (gm >= NN) gm = NN - 1;
        if constexpr (GATHER) {
            ioff[i] = ((c * 8) / CIN) * NN + gm;
            koff[i] = (c * 8) & (CIN - 1);
        } else {
            gmr[i] = gm;
            coff[i] = c * 8;
        }
    }

    bf16x8 bfr[2][NT][4];
    int myIdx[GATHER ? 3 : 1][GATHER ? D : 1];

    const __bf16* wlane = Wsw + ((size_t)(col0 + wc * WN + ml) + (size_t)kh * COUT_TOT) * 8;

    auto loadB = [&](auto sc) {
        constexpr int s = decltype(sc)::value;
        if constexpr (s < NSTEP) {
#pragma unroll
            for (int ni = 0; ni < NT; ++ni)
#pragma unroll
                for (int ks = 0; ks < 4; ++ks)
                    bfr[s & 1][ni][ks] = *(const bf16x8*)(wlane
                        + (size_t)(s * 8 + ks * 2) * COUT_TOT * 8 + ni * 32 * 8);
        }
    };
    auto loadIdxS = [&](auto sc) {
        constexpr int s = decltype(sc)::value;
        if constexpr (GATHER && s < NSTEP) {
#pragma unroll
            for (int i = 0; i < D; ++i)
                myIdx[s % 3][i] = idxT[(s * IPS) * NN + ioff[i]];
        }
    };
    auto issueDMA = [&](auto sc) {
        constexpr int s = decltype(sc)::value;
        if constexpr (s < NSTEP) {
            char* base = Aw + (s % NBUFS) * (WM * 128);
#pragma unroll
            for (int i = 0; i < D; ++i) {
                const __bf16* src;
                if constexpr (GATHER)
                    src = hin + (size_t)myIdx[s % 3][i] * CIN + koff[i];
                else
                    src = hin + (size_t)gmr[i] * K + s * 64 + coff[i];
                __builtin_amdgcn_global_load_lds(
                    (const __attribute__((address_space(1))) void*)src,
                    (__attribute__((address_space(3))) void*)(base + i * 1024),
                    16, 0, 0);
            }
        }
    };

    f32x16 acc[MT][NT];
#pragma unroll
    for (int mi = 0; mi < MT; ++mi)
#pragma unroll
        for (int ni = 0; ni < NT; ++ni) { f32x16 z = {}; acc[mi][ni] = z; }

    // ---- prologue (mirrors in-loop group order so vmcnt counts stay exact)
    loadIdxS(ic<0>{});
    loadIdxS(ic<1>{});
    memfence_sched();
    loadB(ic<0>{});
    memfence_sched();
    issueDMA(ic<0>{});
    memfence_sched();
    loadIdxS(ic<2>{});
    memfence_sched();

    // ---- K-loop: [B(s+1)] [DMA(s+1)] [idx(s+3)] | wait DMA(s) | ds_read + MFMA
    static_for<NSTEP>([&](auto sc) {
        constexpr int s = decltype(sc)::value;
        loadB(ic<s + 1>{});
        memfence_sched();
        issueDMA(ic<s + 1>{});
        memfence_sched();
        loadIdxS(ic<s + 3>{});
        memfence_sched();
        // ops younger than DMA(s)'s last inst:
        //   [step s-1 / prologue]: idx(s+2); [step s]: B(s+1), DMA(s+1), idx(s+3)
        constexpr int NW = I * (s + 2 < NSTEP) + (Bn + D) * (s + 1 < NSTEP)
                         + I * (s + 3 < NSTEP);
        wait_vmcnt<NW>();                      // A(s) now resident in this wave's LDS buf
        memfence_sched();

        const char* base = Aw + (s % NBUFS) * (WM * 128);
        bf16x8 afr[MT][4];
#pragma unroll
        for (int mi = 0; mi < MT; ++mi)
#pragma unroll
            for (int ks = 0; ks < 4; ++ks) {
                int cb = ks * 2 + kh;
                afr[mi][ks] = *(const bf16x8*)(base + ((mi * 32 + ml) * 8 + (cb ^ (ml & 7))) * 16);
            }
#pragma unroll
        for (int ks = 0; ks < 4; ++ks)
#pragma unroll
            for (int mi = 0; mi < MT; ++mi)
#pragma unroll
                for (int ni = 0; ni < NT; ++ni)
                    acc[mi][ni] = __builtin_amdgcn_mfma_f32_32x32x16_bf16(
                        afr[mi][ks], bfr[s & 1][ni][ks], acc[mi][ni], 0, 0, 0);
    });

    // ---- epilogue: acc -> LDS (reuse A region) -> coalesced int4 stores
    __syncthreads();
    __bf16* Cs = (__bf16*)smem;
    constexpr int LDC = COUT_B + 8;
#pragma unroll
    for (int ni = 0; ni < NT; ++ni) {
        const int col = wc * WN + ni * 32 + ml;
        const float bv = bias[col0 + col];
#pragma unroll
        for (int mi = 0; mi < MT; ++mi) {
#pragma unroll
            for (int r = 0; r < 16; ++r) {
                int row = wr * WM + mi * 32 + ((r & 3) + 8 * (r >> 2) + 4 * kh);
                Cs[row * LDC + col] = (__bf16)elu_f(acc[mi][ni][r] + bv);
            }
        }
    }
    __syncthreads();
    constexpr int C8 = COUT_B / 8;
#pragma unroll
    for (int j2 = tid; j2 < TILE_M * C8; j2 += 256) {
        int row = j2 / C8, c8 = j2 % C8;
        int gm = m0 + row;
        if (gm < NN)
            *(int4*)&hout[(size_t)gm * COUT_TOT + col0 + c8 * 8] = *(int4*)&Cs[row * LDC + c8 * 8];
    }
}

// ---------------------------------------------------------------- fc2 + log_softmax: [N,256] bf16 -> [N,12] f32
__global__ __launch_bounds__(256) void fc2_kernel(const __bf16* __restrict__ h4,
                                                  const __bf16* __restrict__ Wb,  // [12,256] bf16
                                                  const float* __restrict__ bias,
                                                  float* __restrict__ out, int N)
{
    const int lane = threadIdx.x & 63;
    const int w = threadIdx.x >> 6;
    const int c = lane & 31;
    const int half = lane >> 5;

    bf16x8 wreg[12];
#pragma unroll
    for (int o = 0; o < 12; ++o)
        wreg[o] = *(const bf16x8*)&Wb[o * 256 + c * 8];

    const int base = blockIdx.x * 32 + w * 8;
#pragma unroll
    for (int p = 0; p < 4; ++p) {
        int n = base + p * 2 + half;
        bool valid = n < N;
        int nn = valid ? n : N - 1;
        bf16x8 h = *(const bf16x8*)&h4[(size_t)nn * 256 + c * 8];
        float hf[8];
#pragma unroll
        for (int j = 0; j < 8; ++j) hf[j] = (float)h[j];
        float pr[12];
#pragma unroll
        for (int o = 0; o < 12; ++o) {
            float s = 0.f;
#pragma unroll
            for (int j = 0; j < 8; ++j) s += hf[j] * (float)wreg[o][j];
            pr[o] = s;
        }
#pragma unroll
        for (int off = 16; off > 0; off >>= 1) {
#pragma unroll
            for (int o = 0; o < 12; ++o) pr[o] += __shfl_down(pr[o], off, 32);
        }
        if (c == 0 && valid) {
            float logits[12], mx = -1e30f;
#pragma unroll
            for (int o = 0; o < 12; ++o) {
                logits[o] = pr[o] + bias[o];
                mx = fmaxf(mx, logits[o]);
            }
            float s = 0.f;
#pragma unroll
            for (int o = 0; o < 12; ++o) s += expf(logits[o] - mx);
            float lse = mx + logf(s);
#pragma unroll
            for (int o = 0; o < 12; ++o) out[(size_t)n * 12 + o] = logits[o] - lse;
        }
    }
}

extern "C" void kernel_launch(void* const* d_in, const int* in_sizes, int n_in,
                              void* d_out, int out_size, void* d_ws, size_t ws_size,
                              hipStream_t stream)
{
    const int N = 100000;
    const float* x     = (const float*)d_in[0];
    const int*   idx   = (const int*)  d_in[1];
    const float* fc0_w = (const float*)d_in[2];
    const float* fc0_b = (const float*)d_in[3];
    const float* w1    = (const float*)d_in[4];
    const float* b1    = (const float*)d_in[5];
    const float* w2    = (const float*)d_in[6];
    const float* b2    = (const float*)d_in[7];
    const float* w3    = (const float*)d_in[8];
    const float* b3    = (const float*)d_in[9];
    const float* fc1_w = (const float*)d_in[10];
    const float* fc1_b = (const float*)d_in[11];
    const float* fc2_w = (const float*)d_in[12];
    const float* fc2_b = (const float*)d_in[13];
    float* out = (float*)d_out;

    // ---- workspace layout
    char* ws = (char*)d_ws;
    const int n_w1 = 32 * 256, n_w2 = 64 * 512, n_w3 = 128 * 1024, n_fc1 = 256 * 128, n_fc2 = 12 * 256;
    const int n_wb = n_w1 + n_w2 + n_w3 + n_fc1 + n_fc2;   // 207872
    __bf16* w1b = (__bf16*)ws;
    __bf16* w2b = w1b + n_w1;
    __bf16* w3b = w2b + n_w2;
    __bf16* f1b = w3b + n_w3;
    __bf16* f2b = f1b + n_fc1;
    size_t off = ((size_t)n_wb * 2 + 4095) & ~(size_t)4095;
    int* idxT = (int*)(ws + off);      off += (size_t)N * 16 * 4;
    __bf16* h0 = (__bf16*)(ws + off);  off += (size_t)N * 16 * 2;
    __bf16* h1 = (__bf16*)(ws + off);  off += (size_t)N * 32 * 2;
    __bf16* h2 = (__bf16*)(ws + off);  off += (size_t)N * 64 * 2;
    __bf16* h3 = (__bf16*)(ws + off);  off += (size_t)N * 128 * 2;
    __bf16* h4 = (__bf16*)(ws + off);  off += (size_t)N * 256 * 2;

    cvt_swz_kernel<<<(n_wb + 255) / 256, 256, 0, stream>>>(w1, w2, w3, fc1_w, fc2_w,
                                                           w1b, w2b, w3b, f1b, f2b);
    idxT_kernel<<<(N * 16 + 255) / 256, 256, 0, stream>>>(idx, idxT, N);
    fc0_kernel<<<(N + 255) / 256, 256, 0, stream>>>(x, fc0_w, fc0_b, h0, N);

    // spiral1: 16ch x16 -> 32. TILE 128 (RW=4, CW=1), wave 32x32, NSTEP=4.  [R8 config]
    mfma_layer<16, 16, 32, 32, 128, 4, 1, true, 3, 100000>
        <<<dim3((N + 127) / 128, 1), 256, 0, stream>>>(h0, idxT, w1b, b1, h1);
    // spiral2: 32ch x16 -> 64. TILE 128 (RW=4, CW=1), wave 32x64, NSTEP=8.  [NEW: A dedup]
    mfma_layer<32, 16, 64, 64, 128, 4, 1, true, 3, 100000>
        <<<dim3((N + 127) / 128, 1), 256, 0, stream>>>(h1, idxT, w2b, b2, h2);
    // spiral3: 64ch x16 -> 128. TILE 64 (RW=2, CW=2), wave 32x64, NSTEP=16. [R8 config]
    mfma_layer<64, 16, 128, 128, 64, 2, 2, true, 3, 100000>
        <<<dim3((N + 63) / 64, 1), 256, 0, stream>>>(h2, idxT, w3b, b3, h3);
    // fc1: dense 128 -> 256, 2 column-blocks of 128. TILE 64, NSTEP=2.      [R8 config]
    mfma_layer<128, 1, 128, 256, 64, 2, 2, false, 4, 100000>
        <<<dim3((N + 63) / 64, 2), 256, 0, stream>>>(h3, nullptr, f1b, fc1_b, h4);
    // fc2 + log_softmax
    fc2_kernel<<<(N + 31) / 32, 256, 0, stream>>>(h4, f2b, fc2_b, out, N);
}